// Round 13
// baseline (1642.953 us; speedup 1.0000x reference)
//
#include <hip/hip_runtime.h>

#define HN 192
#define TT 2048
#define NCLS 12
#define ROWB 768
// LDS layout (bytes)
#define L0_PAD    147456           // 2048B zero region (pad reads land here)
#define LIST0A    149504           // each list: 1024B data slots + 256B junk
#define LIST0B    150784
#define LIST1A    152064
#define LIST1B    153344
#define S0A       154624           // 2 x 768B parity buffers
#define S0B       156160
#define FEATA     157696
#define FEATB     158464
#define LDS_TOTAL 159232

// ws layout (floats): [w0 rows 0..191][zero row][w1 rows 0..191][1024B pad]
__global__ void snn_pack_k(const float* __restrict__ Wc, float* __restrict__ ws) {
  int idx = blockIdx.x * 256 + threadIdx.x;
  if (idx < HN * HN) {                       // layer 0: Wc[0][i][j] -> ws[j*192+i]
    int i = idx / HN, j = idx % HN;
    ws[j * HN + i] = Wc[idx];
  } else if (idx < 2 * HN * HN) {            // layer 1 -> rows 193..384
    int r = idx - HN * HN;
    int i = r / HN, j = r % HN;
    ws[(193 + j) * HN + i] = Wc[idx];
  } else {
    int r = idx - 2 * HN * HN;
    if (r < HN) ws[192 * HN + r] = 0.0f;     // zero row
    if (r < 256) ws[385 * HN + r] = 0.0f;    // tail pad
  }
}

__device__ __forceinline__ float4 add4(float4 a, float4 b) {
  return make_float4(a.x + b.x, a.y + b.y, a.z + b.z, a.w + b.w);
}
__device__ __forceinline__ int lanecnt_lt(unsigned long long m) {
  return __builtin_amdgcn_mbcnt_hi((unsigned)(m >> 32),
           __builtin_amdgcn_mbcnt_lo((unsigned)m, 0u));
}

#define READC(da, db, base, c) do { \
  da = *(const int4*)((base) + (c) * 32); \
  db = *(const int4*)((base) + (c) * 32 + 16); } while (0)

#define ISS8Q(p, ca, cb, basep) do { \
  p##0 = *(const float4*)((basep) + (unsigned)(ca).x + ln16); \
  p##1 = *(const float4*)((basep) + (unsigned)(ca).y + ln16); \
  p##2 = *(const float4*)((basep) + (unsigned)(ca).z + ln16); \
  p##3 = *(const float4*)((basep) + (unsigned)(ca).w + ln16); \
  p##4 = *(const float4*)((basep) + (unsigned)(cb).x + ln16); \
  p##5 = *(const float4*)((basep) + (unsigned)(cb).y + ln16); \
  p##6 = *(const float4*)((basep) + (unsigned)(cb).z + ln16); \
  p##7 = *(const float4*)((basep) + (unsigned)(cb).w + ln16); } while (0)

#define CONS8Q(acc, p) acc = add4(acc, \
  add4(add4(add4(p##0, p##1), add4(p##2, p##3)), \
       add4(add4(p##4, p##5), add4(p##6, p##7))))

// overflow gathers (rare): synchronous chunk re-read + gather
#define OVF(nX, listB, accv, basep) \
  if (nX > 16) { \
    int4 ea_, eb_; \
    float4 r0, r1, r2, r3, r4, r5, r6, r7; \
    READC(ea_, eb_, listB, 2); \
    ISS8Q(r, ea_, eb_, basep); \
    CONS8Q(accv, r); \
    if (nX > 24) { READC(ea_, eb_, listB, 3); ISS8Q(r, ea_, eb_, basep); CONS8Q(accv, r); } \
    if (nX > 32) { \
      _Pragma("unroll 1") \
      for (int g_ = 4; g_ * 8 < nX; ++g_) { \
        READC(ea_, eb_, listB, g_); ISS8Q(r, ea_, eb_, basep); CONS8Q(accv, r); } \
    } \
  }

// LIF layer 0 + s0 publish + branchless compaction (r10 idiom)
#define LIF0_BLOCK(zarr, a0v, v0k, s0f, pout, listB, s0dst) do { \
  const float a0arr_[4] = {(a0v).x, (a0v).y, (a0v).z, (a0v).w}; \
  bool s0_, s1_, s2_, s3_; \
  unsigned long long m0_, m1_, m2_, m3_; \
  { float u_, v_; \
    u_ = zarr[0] + a0arr_[0]; v_ = v0k[0] + (u_ - v0k[0]) * 0.5f; \
    s0_ = (v_ >= 1.0f); m0_ = __ballot(s0_ ? 1 : 0); \
    s0f[0] = s0_ ? 1.0f : 0.0f; v0k[0] = s0_ ? 0.0f : v_; \
    u_ = zarr[1] + a0arr_[1]; v_ = v0k[1] + (u_ - v0k[1]) * 0.5f; \
    s1_ = (v_ >= 1.0f); m1_ = __ballot(s1_ ? 1 : 0); \
    s0f[1] = s1_ ? 1.0f : 0.0f; v0k[1] = s1_ ? 0.0f : v_; \
    u_ = zarr[2] + a0arr_[2]; v_ = v0k[2] + (u_ - v0k[2]) * 0.5f; \
    s2_ = (v_ >= 1.0f); m2_ = __ballot(s2_ ? 1 : 0); \
    s0f[2] = s2_ ? 1.0f : 0.0f; v0k[2] = s2_ ? 0.0f : v_; \
    u_ = zarr[3] + a0arr_[3]; v_ = v0k[3] + (u_ - v0k[3]) * 0.5f; \
    s3_ = (v_ >= 1.0f); m3_ = __ballot(s3_ ? 1 : 0); \
    s0f[3] = s3_ ? 1.0f : 0.0f; v0k[3] = s3_ ? 0.0f : v_; } \
  if (ln < 48) *(float4*)(s0dst) = make_float4(s0f[0], s0f[1], s0f[2], s0f[3]); \
  const int q0_   = (int)__popcll(m0_); \
  const int q01_  = q0_  + (int)__popcll(m1_); \
  const int q012_ = q01_ + (int)__popcll(m2_); \
  pout = q012_ + (int)__popcll(m3_); \
  const int jk_ = 256 + ln; int s_; \
  s_ = s0_ ? lanecnt_lt(m0_)           : jk_; *(int*)((listB) + 4 * s_) = vo; \
  s_ = s1_ ? (q0_   + lanecnt_lt(m1_)) : jk_; *(int*)((listB) + 4 * s_) = vo + ROWB; \
  s_ = s2_ ? (q01_  + lanecnt_lt(m2_)) : jk_; *(int*)((listB) + 4 * s_) = vo + 2 * ROWB; \
  s_ = s3_ ? (q012_ + lanecnt_lt(m3_)) : jk_; *(int*)((listB) + 4 * s_) = vo + 3 * ROWB; \
  *(int*)((listB) + 4 * (pout + ln)) = L0_PAD; \
} while (0)

// LIF layer 1 + count + branchless compaction (pad value 0 -> zero row)
#define LIF1_BLOCK(a1arr, v1k, cntk, pout, listB) do { \
  bool s0_, s1_, s2_, s3_; \
  unsigned long long m0_, m1_, m2_, m3_; \
  float w_; \
  { float u_, v_; \
    u_ = b1z[0] + a1arr[0]; v_ = v1k[0] + (u_ - v1k[0]) * 0.5f; \
    s0_ = (v_ >= 1.0f); m0_ = __ballot(s0_ ? 1 : 0); \
    w_ = s0_ ? 1.0f : 0.0f; cntk[0] += w_; v1k[0] = s0_ ? 0.0f : v_; \
    u_ = b1z[1] + a1arr[1]; v_ = v1k[1] + (u_ - v1k[1]) * 0.5f; \
    s1_ = (v_ >= 1.0f); m1_ = __ballot(s1_ ? 1 : 0); \
    w_ = s1_ ? 1.0f : 0.0f; cntk[1] += w_; v1k[1] = s1_ ? 0.0f : v_; \
    u_ = b1z[2] + a1arr[2]; v_ = v1k[2] + (u_ - v1k[2]) * 0.5f; \
    s2_ = (v_ >= 1.0f); m2_ = __ballot(s2_ ? 1 : 0); \
    w_ = s2_ ? 1.0f : 0.0f; cntk[2] += w_; v1k[2] = s2_ ? 0.0f : v_; \
    u_ = b1z[3] + a1arr[3]; v_ = v1k[3] + (u_ - v1k[3]) * 0.5f; \
    s3_ = (v_ >= 1.0f); m3_ = __ballot(s3_ ? 1 : 0); \
    w_ = s3_ ? 1.0f : 0.0f; cntk[3] += w_; v1k[3] = s3_ ? 0.0f : v_; } \
  const int q0_   = (int)__popcll(m0_); \
  const int q01_  = q0_  + (int)__popcll(m1_); \
  const int q012_ = q01_ + (int)__popcll(m2_); \
  pout = q012_ + (int)__popcll(m3_); \
  const int jk_ = 256 + ln; int s_; \
  s_ = s0_ ? lanecnt_lt(m0_)           : jk_; *(int*)((listB) + 4 * s_) = vo + ROWB; \
  s_ = s1_ ? (q0_   + lanecnt_lt(m1_)) : jk_; *(int*)((listB) + 4 * s_) = vo + 2 * ROWB; \
  s_ = s2_ ? (q01_  + lanecnt_lt(m2_)) : jk_; *(int*)((listB) + 4 * s_) = vo + 3 * ROWB; \
  s_ = s3_ ? (q012_ + lanecnt_lt(m3_)) : jk_; *(int*)((listB) + 4 * s_) = vo + 4 * ROWB; \
  *(int*)((listB) + 4 * (pout + ln)) = 0; \
} while (0)

// 2 waves per block, TWO batch elements per block (A, B) interleaved on each
// wave: wave0 = layer-0 for A and B; wave1 = layer-1 (one-step lagged) for A
// and B.  Batch A's DS/VMEM latencies hide under batch B's instruction stream
// and vice versa; one barrier per TWO batch-steps.
__global__ __launch_bounds__(128, 1) void snn_main_k(
    const float* __restrict__ x, const float* __restrict__ W_in,
    const float* __restrict__ b_in, const float* __restrict__ b_cells,
    const float* __restrict__ W_head, const float* __restrict__ b_head,
    const float* __restrict__ ws, float* __restrict__ out)
{
  extern __shared__ char lds[];
  const int tid = threadIdx.x;
  const int ln  = tid & 63;
  const bool isW0 = (tid < 64);
  const int bA  = 2 * blockIdx.x;
  const int bB  = bA + 1;
  const unsigned ln16 = (unsigned)ln << 4;
  const char* ldsb = lds;
  char* list0Ab = lds + LIST0A;
  char* list0Bb = lds + LIST0B;
  char* list1Ab = lds + LIST1A;
  char* list1Bb = lds + LIST1B;
  const char* w1zb = (const char*)ws + 192 * ROWB;   // zero row = L1 offset base

  // stage W0 (9216 float4) + 2048B zero guard (both waves)
  {
    const float4* src = (const float4*)ws;
    float4* dst = (float4*)lds;
    for (int i = tid; i < (192 * ROWB) / 16; i += 128) dst[i] = src[i];
    ((float4*)(lds + L0_PAD))[tid] = make_float4(0.f, 0.f, 0.f, 0.f);
  }
  __syncthreads();

  // opaque zero: forces x loads to VMEM so lgkm counter stays purely DS
  int vz;
  asm volatile("v_mov_b32 %0, 0" : "=v"(vz));

  // per-lane constants (same weights for both batches)
  float wi0[4], wi1[4], wi2[4], zb[4], b1z[4];
  #pragma unroll
  for (int k = 0; k < 4; ++k) {
    int i = 4 * ln + k;
    bool a = (i < HN);
    int ii = a ? i : 0;
    wi0[k] = a ? W_in[ii * 3 + 0] : 0.f;
    wi1[k] = a ? W_in[ii * 3 + 1] : 0.f;
    wi2[k] = a ? W_in[ii * 3 + 2] : 0.f;
    zb[k]  = a ? (b_in[ii] + b_cells[ii]) : -1e30f;
    b1z[k] = a ? b_cells[HN + ii] : -1e30f;
  }
  const float* __restrict__ xbA = x + (size_t)bA * TT * 3;
  const float* __restrict__ xbB = x + (size_t)bB * TT * 3;
  const int vo = ln * 3072;

  // wave0 state (both batches)
  float v0A[4] = {0, 0, 0, 0}, v0B[4] = {0, 0, 0, 0};
  int nA = 0, nB = 0;
  int4 cA0a = {L0_PAD,L0_PAD,L0_PAD,L0_PAD}, cA0b = cA0a, cA1a = cA0a, cA1b = cA0a;
  int4 cB0a = cA0a, cB0b = cA0a, cB1a = cA0a, cB1b = cA0a;
  float xA0 = xbA[vz + 0], xA1 = xbA[vz + 1], xA2 = xbA[vz + 2];
  float xB0 = xbB[vz + 0], xB1 = xbB[vz + 1], xB2 = xbB[vz + 2];
  // wave1 state (both batches)
  float v1A[4] = {0, 0, 0, 0}, cntA[4] = {0, 0, 0, 0};
  float v1B[4] = {0, 0, 0, 0}, cntB[4] = {0, 0, 0, 0};
  int n1A = 0, n1B = 0;
  float4 gAA0,gAA1,gAA2,gAA3,gAA4,gAA5,gAA6,gAA7;
  float4 gBA0,gBA1,gBA2,gBA3,gBA4,gBA5,gBA6,gBA7;
  float4 gAB0,gAB1,gAB2,gAB3,gAB4,gAB5,gAB6,gAB7;
  float4 gBB0,gBB1,gBB2,gBB3,gBB4,gBB5,gBB6,gBB7;
  if (!isW0) {
    int4 dz = {0, 0, 0, 0};                 // initial pad gathers (zero row)
    ISS8Q(gAA, dz, dz, w1zb);
    ISS8Q(gAB, dz, dz, w1zb);
    gBA0=gBA1=gBA2=gBA3=gBA4=gBA5=gBA6=gBA7=make_float4(0.f,0.f,0.f,0.f);
    gBB0=gBB1=gBB2=gBB3=gBB4=gBB5=gBB6=gBB7=gBA0;
  }

  #pragma unroll 1
  for (int i = 0; i <= TT; ++i) {
    if (isW0) {
      if (i < TT) {
        // ======== wave 0: layer-0 step i, batches A and B ========
        const int wp = i & 1;
        float4 a0vA = make_float4(0.f, 0.f, 0.f, 0.f), a0vB = a0vA;
        float4 hAA0,hAA1,hAA2,hAA3,hAA4,hAA5,hAA6,hAA7;
        float4 hBA0,hBA1,hBA2,hBA3,hBA4,hBA5,hBA6,hBA7;
        float4 hAB0,hAB1,hAB2,hAB3,hAB4,hAB5,hAB6,hAB7;
        float4 hBB0,hBB1,hBB2,hBB3,hBB4,hBB5,hBB6,hBB7;
        // issue both batches' gathers back-to-back (latencies overlap)
        ISS8Q(hAA, cA0a, cA0b, ldsb);
        if (nA > 8) ISS8Q(hBA, cA1a, cA1b, ldsb);
        ISS8Q(hAB, cB0a, cB0b, ldsb);
        if (nB > 8) ISS8Q(hBB, cB1a, cB1b, ldsb);
        // input projections + next-x prefetch (VMEM, in flight)
        float zA[4], zB[4];
        #pragma unroll
        for (int k = 0; k < 4; ++k) {
          zA[k] = xA0 * wi0[k] + xA1 * wi1[k] + xA2 * wi2[k] + zb[k];
          zB[k] = xB0 * wi0[k] + xB1 * wi1[k] + xB2 * wi2[k] + zb[k];
        }
        const int tn = (i + 1 < TT) ? i + 1 : 0;
        const float nxA0 = xbA[tn * 3 + vz + 0];
        const float nxA1 = xbA[tn * 3 + vz + 1];
        const float nxA2 = xbA[tn * 3 + vz + 2];
        const float nxB0 = xbB[tn * 3 + vz + 0];
        const float nxB1 = xbB[tn * 3 + vz + 1];
        const float nxB2 = xbB[tn * 3 + vz + 2];
        // consume
        CONS8Q(a0vA, hAA);
        if (nA > 8) CONS8Q(a0vA, hBA);
        OVF(nA, list0Ab, a0vA, ldsb);
        CONS8Q(a0vB, hAB);
        if (nB > 8) CONS8Q(a0vB, hBB);
        OVF(nB, list0Bb, a0vB, ldsb);
        // LIF + publish + compact, both batches
        float s0fA[4], s0fB[4];
        int pA, pB;
        LIF0_BLOCK(zA, a0vA, v0A, s0fA, pA, list0Ab, lds + S0A + wp * 768 + ln16);
        LIF0_BLOCK(zB, a0vB, v0B, s0fB, pB, list0Bb, lds + S0B + wp * 768 + ln16);
        nA = pA; nB = pB;
        asm volatile("" ::: "memory");
        READC(cA0a, cA0b, list0Ab, 0);
        READC(cA1a, cA1b, list0Ab, 1);
        READC(cB0a, cB0b, list0Bb, 0);
        READC(cB1a, cB1b, list0Bb, 1);
        // all writes retired; only the 8 chunk reads may stay outstanding
        asm volatile("s_waitcnt lgkmcnt(8)" ::: "memory");
        xA0 = nxA0; xA1 = nxA1; xA2 = nxA2;
        xB0 = nxB0; xB1 = nxB1; xB2 = nxB2;
      }
    } else {
      if (i > 0) {
        // ======== wave 1: layer-1 step i-1, batches A and B ========
        const int rp = (i - 1) & 1;
        const float4 s0vA = *(const float4*)(lds + S0A + rp * 768 + ln16);
        const float4 s0vB = *(const float4*)(lds + S0B + rp * 768 + ln16);
        float4 a1vA = make_float4(0.f, 0.f, 0.f, 0.f), a1vB = a1vA;
        CONS8Q(a1vA, gAA);
        if (n1A > 8) CONS8Q(a1vA, gBA);
        OVF(n1A, list1Ab, a1vA, w1zb);
        CONS8Q(a1vB, gAB);
        if (n1B > 8) CONS8Q(a1vB, gBB);
        OVF(n1B, list1Bb, a1vB, w1zb);
        const float a1A[4] = {a1vA.x + s0vA.x, a1vA.y + s0vA.y,
                              a1vA.z + s0vA.z, a1vA.w + s0vA.w};
        const float a1B[4] = {a1vB.x + s0vB.x, a1vB.y + s0vB.y,
                              a1vB.z + s0vB.z, a1vB.w + s0vB.w};
        int pA, pB;
        LIF1_BLOCK(a1A, v1A, cntA, pA, list1Ab);
        LIF1_BLOCK(a1B, v1B, cntB, pB, list1Bb);
        if (i < TT) {
          int4 dA0a, dA0b, dA1a, dA1b, dB0a, dB0b, dB1a, dB1b;
          asm volatile("" ::: "memory");
          READC(dA0a, dA0b, list1Ab, 0);
          READC(dA1a, dA1b, list1Ab, 1);
          READC(dB0a, dB0b, list1Bb, 0);
          READC(dB1a, dB1b, list1Bb, 1);
          ISS8Q(gAA, dA0a, dA0b, w1zb);            // fly across next iteration
          if (pA > 8) ISS8Q(gBA, dA1a, dA1b, w1zb);
          ISS8Q(gAB, dB0a, dB0b, w1zb);
          if (pB > 8) ISS8Q(gBB, dB1a, dB1b, w1zb);
        }
        n1A = pA; n1B = pB;
      }
    }
    asm volatile("" ::: "memory");
    __builtin_amdgcn_s_barrier();
    __builtin_amdgcn_sched_barrier(0);
    asm volatile("" ::: "memory");
  }

  __syncthreads();
  // epilogue: exact means (count * 2^-11) + head GEMVs (one batch per wave)
  if (!isW0 && ln < 48) {
    const float r = 1.0f / 2048.0f;
    ((float4*)(lds + FEATA))[ln] = make_float4(cntA[0]*r, cntA[1]*r, cntA[2]*r, cntA[3]*r);
    ((float4*)(lds + FEATB))[ln] = make_float4(cntB[0]*r, cntB[1]*r, cntB[2]*r, cntB[3]*r);
  }
  __syncthreads();
  if (tid < NCLS) {
    const float* fA = (const float*)(lds + FEATA);
    float a = b_head[tid];
    const float* wh = W_head + tid * HN;
    #pragma unroll 8
    for (int q = 0; q < HN; ++q) a += fA[q] * wh[q];
    out[bA * NCLS + tid] = a;
  } else if (tid >= 64 && tid < 64 + NCLS) {
    const int c = tid - 64;
    const float* fB = (const float*)(lds + FEATB);
    float a = b_head[c];
    const float* wh = W_head + c * HN;
    #pragma unroll 8
    for (int q = 0; q < HN; ++q) a += fB[q] * wh[q];
    out[bB * NCLS + c] = a;
  }
}

extern "C" void kernel_launch(void* const* d_in, const int* in_sizes, int n_in,
                              void* d_out, int out_size, void* d_ws, size_t ws_size,
                              hipStream_t stream) {
  const float* x       = (const float*)d_in[0];
  const float* W_in    = (const float*)d_in[1];
  const float* b_in    = (const float*)d_in[2];
  const float* W_cells = (const float*)d_in[3];
  const float* b_cells = (const float*)d_in[4];
  const float* W_head  = (const float*)d_in[5];
  const float* b_head  = (const float*)d_in[6];
  float* out = (float*)d_out;
  float* ws  = (float*)d_ws;   // 296704 bytes used

  snn_pack_k<<<(2 * HN * HN + 512 + 255) / 256, 256, 0, stream>>>(W_cells, ws);
  snn_main_k<<<64, 128, LDS_TOTAL, stream>>>(
      x, W_in, b_in, b_cells, W_head, b_head, ws, out);
}

// Round 14
// 1290.863 us; speedup vs baseline: 1.2728x; 1.2728x over previous
//
#include <hip/hip_runtime.h>

#define HN 192
#define TT 2048
#define NCLS 12
#define ROWB 768
// LDS layout (bytes): W0p occupies [0, 150528): 196 rows x 768B
//   rows 0..3 = zero pad rows (ffs-1 == -1 lands there); neuron j at (j+4)*768
#define LDS_S0    150528           // 2 x 768B s0 double buffer (parity)
#define LDS_LIST1 152064           // wave1 list: 1024B data + 256B junk
#define LDS_FEAT  153344           // 768B
#define LDS_TOTAL 154112
// ws float layout: [W0p 196*192][w1 zero row 192][w1 rows (j+1)*192][256 junk]
#define W1OFF 37632                // float offset of w1 zero row

__global__ void snn_pack_k(const float* __restrict__ Wc, float* __restrict__ ws) {
  int id = blockIdx.x * 256 + threadIdx.x;
  if (id < 768) {                                  // W0p pad rows 0..3
    ws[id] = 0.0f;
  } else if (id < 37632) {                         // W0p data: row j at (j+4)*192
    int d = id - 768, j = d / 192, o = d % 192;
    ws[(j + 4) * 192 + o] = Wc[o * 192 + j];       // layer-0 W[o][j]
  } else if (id < 37824) {                         // w1 zero row
    ws[id] = 0.0f;
  } else if (id < 74688) {                         // w1 data: row j at W1OFF+(j+1)*192
    int d = id - 37824, j = d / 192, o = d % 192;
    ws[W1OFF + (j + 1) * 192 + o] = Wc[36864 + o * 192 + j];
  } else if (id < 74944) {                         // junk tail
    ws[id - 74688 + 74880] = 0.0f;
  }
}

__device__ __forceinline__ float4 add4(float4 a, float4 b) {
  return make_float4(a.x + b.x, a.y + b.y, a.z + b.z, a.w + b.w);
}
__device__ __forceinline__ int lanecnt_lt(unsigned long long m) {
  return __builtin_amdgcn_mbcnt_hi((unsigned)(m >> 32),
           __builtin_amdgcn_mbcnt_lo((unsigned)m, 0u));
}
// force a (wave-uniform) 64-bit mask into SGPRs so extraction stays SALU
__device__ __forceinline__ unsigned long long to_sgpr64(unsigned long long m) {
  unsigned lo = __builtin_amdgcn_readfirstlane((unsigned)m);
  unsigned hi = __builtin_amdgcn_readfirstlane((unsigned)(m >> 32));
  return ((unsigned long long)hi << 32) | lo;
}

#define READC(da, db, base, c) do { \
  da = *(const int4*)((base) + (c) * 32); \
  db = *(const int4*)((base) + (c) * 32 + 16); } while (0)

#define ISS8Q(p, ca, cb, basep) do { \
  p##0 = *(const float4*)((basep) + (unsigned)(ca).x + ln16); \
  p##1 = *(const float4*)((basep) + (unsigned)(ca).y + ln16); \
  p##2 = *(const float4*)((basep) + (unsigned)(ca).z + ln16); \
  p##3 = *(const float4*)((basep) + (unsigned)(ca).w + ln16); \
  p##4 = *(const float4*)((basep) + (unsigned)(cb).x + ln16); \
  p##5 = *(const float4*)((basep) + (unsigned)(cb).y + ln16); \
  p##6 = *(const float4*)((basep) + (unsigned)(cb).z + ln16); \
  p##7 = *(const float4*)((basep) + (unsigned)(cb).w + ln16); } while (0)

#define CONS8Q(acc, p) acc = add4(acc, \
  add4(add4(add4(p##0, p##1), add4(p##2, p##3)), \
       add4(add4(p##4, p##5), add4(p##6, p##7))))

// extract one offset: idx*3072 + wbase; idx=-1 (empty) -> row (wbase/768 - 4)
// = zero pad row.  SALU: s_ff1_i32_b64 + s_add/s_and chain.
#define EXTS(dst, m, wbase) do { \
  dst = (__ffsll((long long)(m)) - 1) * 3072 + (wbase); \
  m &= (m) - 1; } while (0)

// 2 waves per batch, one-step-lagged pipeline.  Wave0 (layer 0): no LDS list
// at all -- ballot masks forced to SGPRs, offsets extracted with 4 independent
// 4-deep s_ff1 chains, and the NEXT step's 16 ds_read_b128 issued BEFORE the
// barrier (latency dies under barrier + preamble).  Leftover spikes (>4 per
// word) carried in scalar masks, gathered synchronously next step (rare).
// Wave1 (layer 1): r10 structure (LDS list + global gather, full-iter flight).
__global__ __launch_bounds__(128, 1) void snn_main_k(
    const float* __restrict__ x, const float* __restrict__ W_in,
    const float* __restrict__ b_in, const float* __restrict__ b_cells,
    const float* __restrict__ W_head, const float* __restrict__ b_head,
    const float* __restrict__ ws, float* __restrict__ out)
{
  extern __shared__ char lds[];
  const int tid = threadIdx.x;
  const int ln  = tid & 63;
  const bool isW0 = (tid < 64);
  const int b   = blockIdx.x;
  const unsigned ln16 = (unsigned)ln << 4;
  const char* ldsb = lds;
  char* list1b = lds + LDS_LIST1;
  float* feat  = (float*)(lds + LDS_FEAT);
  const char* w1zb = (const char*)ws + W1OFF * 4;   // w1 zero row = offset base

  // stage W0p (incl. its 4 zero pad rows) into LDS
  {
    const float4* src = (const float4*)ws;
    float4* dst = (float4*)lds;
    for (int i = tid; i < W1OFF / 4; i += 128) dst[i] = src[i];
  }
  __syncthreads();

  // opaque zero: forces x loads to VMEM so lgkm counter stays purely DS
  int vz;
  asm volatile("v_mov_b32 %0, 0" : "=v"(vz));

  // per-lane constants (4 neurons/lane both layers; lanes 48-63 parked)
  float wi0[4], wi1[4], wi2[4], zb[4], b1z[4];
  #pragma unroll
  for (int k = 0; k < 4; ++k) {
    int i = 4 * ln + k;
    bool a = (i < HN);
    int ii = a ? i : 0;
    wi0[k] = a ? W_in[ii * 3 + 0] : 0.f;
    wi1[k] = a ? W_in[ii * 3 + 1] : 0.f;
    wi2[k] = a ? W_in[ii * 3 + 2] : 0.f;
    zb[k]  = a ? (b_in[ii] + b_cells[ii]) : -1e30f;
    b1z[k] = a ? b_cells[HN + ii] : -1e30f;
  }
  const float* __restrict__ xb = x + (size_t)b * TT * 3;
  const int vo = ln * 3072;

  // wave0 state
  float v0k[4] = {0, 0, 0, 0};
  unsigned long long lm0 = 0, lm1 = 0, lm2 = 0, lm3 = 0;   // leftover masks
  float4 qq0,qq1,qq2,qq3,qq4,qq5,qq6,qq7,qq8,qq9,qq10,qq11,qq12,qq13,qq14,qq15;
  qq0=qq1=qq2=qq3=qq4=qq5=qq6=qq7=make_float4(0.f,0.f,0.f,0.f);
  qq8=qq9=qq10=qq11=qq12=qq13=qq14=qq15=qq0;
  float x0 = xb[vz + 0], x1 = xb[vz + 1], x2 = xb[vz + 2];
  // wave1 state
  float v1k[4] = {0, 0, 0, 0}, cntk[4] = {0, 0, 0, 0};
  int n1 = 0;
  float4 gA0, gA1, gA2, gA3, gA4, gA5, gA6, gA7;
  float4 gB0, gB1, gB2, gB3, gB4, gB5, gB6, gB7;
  if (!isW0) {
    int4 dz = {0, 0, 0, 0};                 // initial pad gather (zero row)
    ISS8Q(gA, dz, dz, w1zb);
    gB0=gB1=gB2=gB3=gB4=gB5=gB6=gB7=make_float4(0.f,0.f,0.f,0.f);
  }

  #pragma unroll 1
  for (int i = 0; i <= TT; ++i) {
    if (isW0) {
      if (i < TT) {
        // ======== wave 0: layer-0 step i ========
        const int wp = i & 1;
        // consume the 16 pre-issued reads (arrived during barrier)
        float4 a0v = add4(add4(add4(add4(qq0,qq1),add4(qq2,qq3)),
                               add4(add4(qq4,qq5),add4(qq6,qq7))),
                          add4(add4(add4(qq8,qq9),add4(qq10,qq11)),
                               add4(add4(qq12,qq13),add4(qq14,qq15))));
        // leftover spikes (rare): 4 separate uniform loops, no mask selects
        if (lm0) { do { int off; EXTS(off, lm0, 3072);
                        a0v = add4(a0v, *(const float4*)(ldsb + (unsigned)off + ln16));
                      } while (lm0); }
        if (lm1) { do { int off; EXTS(off, lm1, 3840);
                        a0v = add4(a0v, *(const float4*)(ldsb + (unsigned)off + ln16));
                      } while (lm1); }
        if (lm2) { do { int off; EXTS(off, lm2, 4608);
                        a0v = add4(a0v, *(const float4*)(ldsb + (unsigned)off + ln16));
                      } while (lm2); }
        if (lm3) { do { int off; EXTS(off, lm3, 5376);
                        a0v = add4(a0v, *(const float4*)(ldsb + (unsigned)off + ln16));
                      } while (lm3); }
        // input projection + next-x prefetch (VMEM, in flight)
        float zarr[4];
        #pragma unroll
        for (int k = 0; k < 4; ++k)
          zarr[k] = x0 * wi0[k] + x1 * wi1[k] + x2 * wi2[k] + zb[k];
        const int tn = (i + 1 < TT) ? i + 1 : 0;
        const float nx0 = xb[tn * 3 + vz + 0];
        const float nx1 = xb[tn * 3 + vz + 1];
        const float nx2 = xb[tn * 3 + vz + 2];
        // LIF layer 0 (exact reference op order), flattened
        const float a0arr[4] = {a0v.x, a0v.y, a0v.z, a0v.w};
        float s0f[4];
        unsigned long long M0, M1, M2, M3;
        {
          float u, v;
          u = zarr[0] + a0arr[0]; v = v0k[0] + (u - v0k[0]) * 0.5f;
          bool s = (v >= 1.0f); M0 = __ballot(s ? 1 : 0);
          s0f[0] = s ? 1.0f : 0.0f; v0k[0] = s ? 0.0f : v;
          u = zarr[1] + a0arr[1]; v = v0k[1] + (u - v0k[1]) * 0.5f;
          bool s1 = (v >= 1.0f); M1 = __ballot(s1 ? 1 : 0);
          s0f[1] = s1 ? 1.0f : 0.0f; v0k[1] = s1 ? 0.0f : v;
          u = zarr[2] + a0arr[2]; v = v0k[2] + (u - v0k[2]) * 0.5f;
          bool s2 = (v >= 1.0f); M2 = __ballot(s2 ? 1 : 0);
          s0f[2] = s2 ? 1.0f : 0.0f; v0k[2] = s2 ? 0.0f : v;
          u = zarr[3] + a0arr[3]; v = v0k[3] + (u - v0k[3]) * 0.5f;
          bool s3 = (v >= 1.0f); M3 = __ballot(s3 ? 1 : 0);
          s0f[3] = s3 ? 1.0f : 0.0f; v0k[3] = s3 ? 0.0f : v;
        }
        // publish s0(i)  (the ONE ds_write; must retire before the barrier)
        if (ln < 48)
          *(float4*)(lds + LDS_S0 + wp * 768 + ln16) =
              make_float4(s0f[0], s0f[1], s0f[2], s0f[3]);
        asm volatile("" ::: "memory");
        // SALU extraction: 4 independent 4-deep s_ff1 chains; leftovers carried
        int of0,of1,of2,of3,of4,of5,of6,of7,of8,of9,of10,of11,of12,of13,of14,of15;
        {
          unsigned long long m0 = to_sgpr64(M0), m1 = to_sgpr64(M1);
          unsigned long long m2 = to_sgpr64(M2), m3 = to_sgpr64(M3);
          EXTS(of0,  m0, 3072); EXTS(of1,  m0, 3072);
          EXTS(of2,  m0, 3072); EXTS(of3,  m0, 3072);
          EXTS(of4,  m1, 3840); EXTS(of5,  m1, 3840);
          EXTS(of6,  m1, 3840); EXTS(of7,  m1, 3840);
          EXTS(of8,  m2, 4608); EXTS(of9,  m2, 4608);
          EXTS(of10, m2, 4608); EXTS(of11, m2, 4608);
          EXTS(of12, m3, 5376); EXTS(of13, m3, 5376);
          EXTS(of14, m3, 5376); EXTS(of15, m3, 5376);
          lm0 = m0; lm1 = m1; lm2 = m2; lm3 = m3;
        }
        // issue next step's 16 gathers -> latency dies under the barrier
        qq0  = *(const float4*)(ldsb + (unsigned)of0  + ln16);
        qq1  = *(const float4*)(ldsb + (unsigned)of1  + ln16);
        qq2  = *(const float4*)(ldsb + (unsigned)of2  + ln16);
        qq3  = *(const float4*)(ldsb + (unsigned)of3  + ln16);
        qq4  = *(const float4*)(ldsb + (unsigned)of4  + ln16);
        qq5  = *(const float4*)(ldsb + (unsigned)of5  + ln16);
        qq6  = *(const float4*)(ldsb + (unsigned)of6  + ln16);
        qq7  = *(const float4*)(ldsb + (unsigned)of7  + ln16);
        qq8  = *(const float4*)(ldsb + (unsigned)of8  + ln16);
        qq9  = *(const float4*)(ldsb + (unsigned)of9  + ln16);
        qq10 = *(const float4*)(ldsb + (unsigned)of10 + ln16);
        qq11 = *(const float4*)(ldsb + (unsigned)of11 + ln16);
        qq12 = *(const float4*)(ldsb + (unsigned)of12 + ln16);
        qq13 = *(const float4*)(ldsb + (unsigned)of13 + ln16);
        qq14 = *(const float4*)(ldsb + (unsigned)of14 + ln16);
        qq15 = *(const float4*)(ldsb + (unsigned)of15 + ln16);
        // wait until <=15 outstanding: the oldest (s0 ds_write) has retired;
        // the 16 reads stay in flight across the barrier (DS retires in order)
        asm volatile("s_waitcnt lgkmcnt(15)" ::: "memory");
        x0 = nx0; x1 = nx1; x2 = nx2;
      }
    } else {
      if (i > 0) {
        // ======== wave 1: layer-1 step i-1 (r10 structure) ========
        const int rp = (i - 1) & 1;
        const float4 s0v = *(const float4*)(lds + LDS_S0 + rp * 768 + ln16);
        float4 a1v = make_float4(0.f, 0.f, 0.f, 0.f);
        CONS8Q(a1v, gA);
        if (n1 > 8) CONS8Q(a1v, gB);
        if (n1 > 16) {
          int4 e2a, e2b;
          float4 r0, r1, r2, r3, r4, r5, r6, r7;
          READC(e2a, e2b, list1b, 2);
          ISS8Q(r, e2a, e2b, w1zb);
          CONS8Q(a1v, r);
          if (n1 > 24) {
            READC(e2a, e2b, list1b, 3);
            ISS8Q(r, e2a, e2b, w1zb);
            CONS8Q(a1v, r);
          }
          if (n1 > 32) {
            #pragma unroll 1
            for (int g = 4; g * 8 < n1; ++g) {
              READC(e2a, e2b, list1b, g);
              ISS8Q(r, e2a, e2b, w1zb);
              CONS8Q(a1v, r);
            }
          }
        }
        const float a1arr[4] = {a1v.x + s0v.x, a1v.y + s0v.y,
                                a1v.z + s0v.z, a1v.w + s0v.w};
        float s1w[4];
        bool sq[4];
        unsigned long long nn0, nn1, nn2, nn3;
        {
          float u, v;
          u = b1z[0] + a1arr[0]; v = v1k[0] + (u - v1k[0]) * 0.5f;
          sq[0] = (v >= 1.0f); nn0 = __ballot(sq[0] ? 1 : 0);
          s1w[0] = sq[0] ? 1.0f : 0.0f; v1k[0] = sq[0] ? 0.0f : v;
          u = b1z[1] + a1arr[1]; v = v1k[1] + (u - v1k[1]) * 0.5f;
          sq[1] = (v >= 1.0f); nn1 = __ballot(sq[1] ? 1 : 0);
          s1w[1] = sq[1] ? 1.0f : 0.0f; v1k[1] = sq[1] ? 0.0f : v;
          u = b1z[2] + a1arr[2]; v = v1k[2] + (u - v1k[2]) * 0.5f;
          sq[2] = (v >= 1.0f); nn2 = __ballot(sq[2] ? 1 : 0);
          s1w[2] = sq[2] ? 1.0f : 0.0f; v1k[2] = sq[2] ? 0.0f : v;
          u = b1z[3] + a1arr[3]; v = v1k[3] + (u - v1k[3]) * 0.5f;
          sq[3] = (v >= 1.0f); nn3 = __ballot(sq[3] ? 1 : 0);
          s1w[3] = sq[3] ? 1.0f : 0.0f; v1k[3] = sq[3] ? 0.0f : v;
        }
        cntk[0] += s1w[0]; cntk[1] += s1w[1]; cntk[2] += s1w[2]; cntk[3] += s1w[3];
        const int r0c  = (int)__popcll(nn0);
        const int r01  = r0c + (int)__popcll(nn1);
        const int r012 = r01 + (int)__popcll(nn2);
        const int p1n  = r012 + (int)__popcll(nn3);
        const int jk = 256 + ln;
        {
          int s;
          s = sq[0] ? lanecnt_lt(nn0)          : jk; *(int*)(list1b + 4 * s) = vo + ROWB;
          s = sq[1] ? (r0c  + lanecnt_lt(nn1)) : jk; *(int*)(list1b + 4 * s) = vo + 2 * ROWB;
          s = sq[2] ? (r01  + lanecnt_lt(nn2)) : jk; *(int*)(list1b + 4 * s) = vo + 3 * ROWB;
          s = sq[3] ? (r012 + lanecnt_lt(nn3)) : jk; *(int*)(list1b + 4 * s) = vo + 4 * ROWB;
        }
        *(int*)(list1b + 4 * (p1n + ln)) = 0;        // pads -> zero row
        if (i < TT) {
          int4 d0a, d0b, d1a, d1b;
          asm volatile("" ::: "memory");
          READC(d0a, d0b, list1b, 0);
          READC(d1a, d1b, list1b, 1);
          ISS8Q(gA, d0a, d0b, w1zb);                 // flies across next step
          if (p1n > 8) ISS8Q(gB, d1a, d1b, w1zb);
        }
        n1 = p1n;
      }
    }
    asm volatile("" ::: "memory");
    __builtin_amdgcn_s_barrier();
    __builtin_amdgcn_sched_barrier(0);
    asm volatile("" ::: "memory");
  }

  __syncthreads();
  // epilogue: exact mean (count * 2^-11) + head GEMV
  if (!isW0 && ln < 48) {
    const float r = 1.0f / 2048.0f;
    ((float4*)feat)[ln] = make_float4(cntk[0] * r, cntk[1] * r, cntk[2] * r, cntk[3] * r);
  }
  __syncthreads();
  if (tid < NCLS) {
    float a = b_head[tid];
    const float* wh = W_head + tid * HN;
    #pragma unroll 8
    for (int q = 0; q < HN; ++q) a += feat[q] * wh[q];
    out[b * NCLS + tid] = a;
  }
}

extern "C" void kernel_launch(void* const* d_in, const int* in_sizes, int n_in,
                              void* d_out, int out_size, void* d_ws, size_t ws_size,
                              hipStream_t stream) {
  const float* x       = (const float*)d_in[0];
  const float* W_in    = (const float*)d_in[1];
  const float* b_in    = (const float*)d_in[2];
  const float* W_cells = (const float*)d_in[3];
  const float* b_cells = (const float*)d_in[4];
  const float* W_head  = (const float*)d_in[5];
  const float* b_head  = (const float*)d_in[6];
  float* out = (float*)d_out;
  float* ws  = (float*)d_ws;   // 300544 bytes used

  snn_pack_k<<<(74944 + 255) / 256, 256, 0, stream>>>(W_cells, ws);
  snn_main_k<<<128, 128, LDS_TOTAL, stream>>>(
      x, W_in, b_in, b_cells, W_head, b_head, ws, out);
}

// Round 15
// 1033.161 us; speedup vs baseline: 1.5902x; 1.2494x over previous
//
#include <hip/hip_runtime.h>

#define HN 192
#define TT 2048
#define NCLS 12
#define ROWB 768
// LDS layout (bytes)
#define L0_PAD    147456           // 2048B zero region (pad reads land here)
#define LIST0     149504           // 1024B data slots + 256B junk
#define LIST1     150784           // same for layer 1
#define RING      152064           // 8 x 768B s0 ring buffer
#define CNT       158208           // prod @ +0, cons @ +64
#define LDS_FEAT  158336           // 768B
#define LDS_TOTAL 159104

// ws layout (floats): [w0 rows 0..191][zero row][w1 rows 0..191][1024B pad]
__global__ void snn_pack_k(const float* __restrict__ Wc, float* __restrict__ ws) {
  int idx = blockIdx.x * 256 + threadIdx.x;
  if (idx < HN * HN) {                       // layer 0: Wc[0][i][j] -> ws[j*192+i]
    int i = idx / HN, j = idx % HN;
    ws[j * HN + i] = Wc[idx];
  } else if (idx < 2 * HN * HN) {            // layer 1 -> rows 193..384
    int r = idx - HN * HN;
    int i = r / HN, j = r % HN;
    ws[(193 + j) * HN + i] = Wc[idx];
  } else {
    int r = idx - 2 * HN * HN;
    if (r < HN) ws[192 * HN + r] = 0.0f;     // zero row
    if (r < 256) ws[385 * HN + r] = 0.0f;    // tail pad
  }
}

__device__ __forceinline__ float4 add4(float4 a, float4 b) {
  return make_float4(a.x + b.x, a.y + b.y, a.z + b.z, a.w + b.w);
}
__device__ __forceinline__ int lanecnt_lt(unsigned long long m) {
  return __builtin_amdgcn_mbcnt_hi((unsigned)(m >> 32),
           __builtin_amdgcn_mbcnt_lo((unsigned)m, 0u));
}

#define READC(da, db, base, c) do { \
  da = *(const int4*)((base) + (c) * 32); \
  db = *(const int4*)((base) + (c) * 32 + 16); } while (0)

#define ISS8Q(p, ca, cb, basep) do { \
  p##0 = *(const float4*)((basep) + (unsigned)(ca).x + ln16); \
  p##1 = *(const float4*)((basep) + (unsigned)(ca).y + ln16); \
  p##2 = *(const float4*)((basep) + (unsigned)(ca).z + ln16); \
  p##3 = *(const float4*)((basep) + (unsigned)(ca).w + ln16); \
  p##4 = *(const float4*)((basep) + (unsigned)(cb).x + ln16); \
  p##5 = *(const float4*)((basep) + (unsigned)(cb).y + ln16); \
  p##6 = *(const float4*)((basep) + (unsigned)(cb).z + ln16); \
  p##7 = *(const float4*)((basep) + (unsigned)(cb).w + ln16); } while (0)

#define CONS8Q(acc, p) acc = add4(acc, \
  add4(add4(add4(p##0, p##1), add4(p##2, p##3)), \
       add4(add4(p##4, p##5), add4(p##6, p##7))))

// Barrier-free producer/consumer: wave0 = layer 0 (LDS W0 gather), wave1 =
// layer 1 (global W1 gather).  s0 flows through an 8-slot LDS ring with
// monotonic prod/cons counters (volatile DS; DS retires in order per wave,
// so slot-write -> prod-write and prod-poll -> slot-read are race-free).
// No __syncthreads in the scan: each wave's loop pipelines freely.
__global__ __launch_bounds__(128, 1) void snn_main_k(
    const float* __restrict__ x, const float* __restrict__ W_in,
    const float* __restrict__ b_in, const float* __restrict__ b_cells,
    const float* __restrict__ W_head, const float* __restrict__ b_head,
    const float* __restrict__ ws, float* __restrict__ out)
{
  extern __shared__ char lds[];
  const int tid = threadIdx.x;
  const int ln  = tid & 63;
  const bool isW0 = (tid < 64);
  const int b   = blockIdx.x;
  const unsigned ln16 = (unsigned)ln << 4;
  const char* ldsb = lds;
  char* list0b = lds + LIST0;
  char* list1b = lds + LIST1;
  float* feat  = (float*)(lds + LDS_FEAT);
  volatile int* vprod = (volatile int*)(lds + CNT);
  volatile int* vcons = (volatile int*)(lds + CNT + 64);
  const char* w1zb = (const char*)ws + 192 * ROWB;   // zero row = L1 offset base

  // stage W0 (9216 float4) + 2048B zero guard + counters (both waves)
  {
    const float4* src = (const float4*)ws;
    float4* dst = (float4*)lds;
    for (int i = tid; i < (192 * ROWB) / 16; i += 128) dst[i] = src[i];
    ((float4*)(lds + L0_PAD))[tid] = make_float4(0.f, 0.f, 0.f, 0.f);
    if (tid == 0) { *vprod = 0; *vcons = 0; }
  }
  __syncthreads();

  // opaque zero: keeps x loads on the VMEM path (vmcnt), DS stays clean
  int vz;
  asm volatile("v_mov_b32 %0, 0" : "=v"(vz));

  // per-lane constants (4 neurons/lane in both layers; lanes 48-63 parked)
  float wi0[4], wi1[4], wi2[4], zb[4], b1z[4];
  #pragma unroll
  for (int k = 0; k < 4; ++k) {
    int i = 4 * ln + k;
    bool a = (i < HN);
    int ii = a ? i : 0;
    wi0[k] = a ? W_in[ii * 3 + 0] : 0.f;
    wi1[k] = a ? W_in[ii * 3 + 1] : 0.f;
    wi2[k] = a ? W_in[ii * 3 + 2] : 0.f;
    zb[k]  = a ? (b_in[ii] + b_cells[ii]) : -1e30f;
    b1z[k] = a ? b_cells[HN + ii] : -1e30f;
  }
  const float* __restrict__ xb = x + (size_t)b * TT * 3;
  const int vo = ln * 3072;

  if (isW0) {
    // ================= wave 0: layer-0 producer =================
    float v0k[4] = {0, 0, 0, 0};
    int n0 = 0, cons_seen = 0;
    int4 c0a = {L0_PAD,L0_PAD,L0_PAD,L0_PAD}, c0b = c0a, c1a = c0a, c1b = c0a;
    float x0 = xb[vz + 0], x1 = xb[vz + 1], x2 = xb[vz + 2];

    #pragma unroll 1
    for (int i = 0; i < TT; ++i) {
      // flow control: stay <= 5 slots ahead of the consumer (ring = 8)
      if (i - cons_seen > 5) {
        cons_seen = *vcons;
        while (i - cons_seen > 5) cons_seen = *vcons;
      }
      // gather step i (chunks read at end of previous iteration)
      float4 a0v = make_float4(0.f, 0.f, 0.f, 0.f);
      float4 hA0, hA1, hA2, hA3, hA4, hA5, hA6, hA7;
      float4 hB0, hB1, hB2, hB3, hB4, hB5, hB6, hB7;
      ISS8Q(hA, c0a, c0b, ldsb);
      if (n0 > 8) ISS8Q(hB, c1a, c1b, ldsb);
      // input projection + next-x prefetch (VMEM, in flight)
      float zarr[4];
      #pragma unroll
      for (int k = 0; k < 4; ++k)
        zarr[k] = x0 * wi0[k] + x1 * wi1[k] + x2 * wi2[k] + zb[k];
      const int tn = (i + 1 < TT) ? i + 1 : 0;
      const float nx0 = xb[tn * 3 + vz + 0];
      const float nx1 = xb[tn * 3 + vz + 1];
      const float nx2 = xb[tn * 3 + vz + 2];
      CONS8Q(a0v, hA);
      if (n0 > 8) CONS8Q(a0v, hB);
      if (n0 > 16) {                           // rare overflow (list still intact)
        int4 e2a, e2b;
        float4 r0, r1, r2, r3, r4, r5, r6, r7;
        READC(e2a, e2b, list0b, 2);
        ISS8Q(r, e2a, e2b, ldsb);
        CONS8Q(a0v, r);
        if (n0 > 24) {
          READC(e2a, e2b, list0b, 3);
          ISS8Q(r, e2a, e2b, ldsb);
          CONS8Q(a0v, r);
        }
        if (n0 > 32) {
          #pragma unroll 1
          for (int g = 4; g * 8 < n0; ++g) {
            READC(e2a, e2b, list0b, g);
            ISS8Q(r, e2a, e2b, ldsb);
            CONS8Q(a0v, r);
          }
        }
      }
      // LIF layer 0 (exact reference op order), flattened
      const float a0arr[4] = {a0v.x, a0v.y, a0v.z, a0v.w};
      float s0f[4];
      bool sp[4];
      unsigned long long mm0, mm1, mm2, mm3;
      {
        float u, v;
        u = zarr[0] + a0arr[0]; v = v0k[0] + (u - v0k[0]) * 0.5f;
        sp[0] = (v >= 1.0f); mm0 = __ballot(sp[0] ? 1 : 0);
        s0f[0] = sp[0] ? 1.0f : 0.0f; v0k[0] = sp[0] ? 0.0f : v;
        u = zarr[1] + a0arr[1]; v = v0k[1] + (u - v0k[1]) * 0.5f;
        sp[1] = (v >= 1.0f); mm1 = __ballot(sp[1] ? 1 : 0);
        s0f[1] = sp[1] ? 1.0f : 0.0f; v0k[1] = sp[1] ? 0.0f : v;
        u = zarr[2] + a0arr[2]; v = v0k[2] + (u - v0k[2]) * 0.5f;
        sp[2] = (v >= 1.0f); mm2 = __ballot(sp[2] ? 1 : 0);
        s0f[2] = sp[2] ? 1.0f : 0.0f; v0k[2] = sp[2] ? 0.0f : v;
        u = zarr[3] + a0arr[3]; v = v0k[3] + (u - v0k[3]) * 0.5f;
        sp[3] = (v >= 1.0f); mm3 = __ballot(sp[3] ? 1 : 0);
        s0f[3] = sp[3] ? 1.0f : 0.0f; v0k[3] = sp[3] ? 0.0f : v;
      }
      // publish s0(i) into ring slot, then bump prod (DS retires in order)
      if (ln < 48)
        *(float4*)(lds + RING + ((i & 7) * 768) + ln16) =
            make_float4(s0f[0], s0f[1], s0f[2], s0f[3]);
      asm volatile("" ::: "memory");
      if (ln == 0) *vprod = i + 1;
      // branchless compaction (junk slots at 256+ln) + pads + chunk re-read
      const int q0   = (int)__popcll(mm0);
      const int q01  = q0  + (int)__popcll(mm1);
      const int q012 = q01 + (int)__popcll(mm2);
      const int p0n  = q012 + (int)__popcll(mm3);
      const int jk = 256 + ln;
      {
        int s;
        s = sp[0] ? lanecnt_lt(mm0)          : jk; *(int*)(list0b + 4 * s) = vo;
        s = sp[1] ? (q0   + lanecnt_lt(mm1)) : jk; *(int*)(list0b + 4 * s) = vo + ROWB;
        s = sp[2] ? (q01  + lanecnt_lt(mm2)) : jk; *(int*)(list0b + 4 * s) = vo + 2 * ROWB;
        s = sp[3] ? (q012 + lanecnt_lt(mm3)) : jk; *(int*)(list0b + 4 * s) = vo + 3 * ROWB;
      }
      *(int*)(list0b + 4 * (p0n + ln)) = L0_PAD;   // unconditional pads
      n0 = p0n;
      asm volatile("" ::: "memory");
      READC(c0a, c0b, list0b, 0);
      READC(c1a, c1b, list0b, 1);
      x0 = nx0; x1 = nx1; x2 = nx2;
    }
  } else {
    // ================= wave 1: layer-1 consumer =================
    float v1k[4] = {0, 0, 0, 0}, cntk[4] = {0, 0, 0, 0};
    int n1 = 0, prod_seen = 0;
    float4 gA0, gA1, gA2, gA3, gA4, gA5, gA6, gA7;
    float4 gB0, gB1, gB2, gB3, gB4, gB5, gB6, gB7;
    {
      int4 dz = {0, 0, 0, 0};                // initial pad gather (zero row)
      ISS8Q(gA, dz, dz, w1zb);
      gB0=gB1=gB2=gB3=gB4=gB5=gB6=gB7=make_float4(0.f,0.f,0.f,0.f);
    }

    #pragma unroll 1
    for (int i = 0; i < TT; ++i) {
      // wait until s0(i) is published
      if (prod_seen <= i) {
        do { prod_seen = *vprod; } while (prod_seen <= i);
      }
      asm volatile("" ::: "memory");
      const float4 s0v = *(const float4*)(lds + RING + ((i & 7) * 768) + ln16);
      // consume W1 gather (issued at end of previous iteration)
      float4 a1v = make_float4(0.f, 0.f, 0.f, 0.f);
      CONS8Q(a1v, gA);
      if (n1 > 8) CONS8Q(a1v, gB);
      if (n1 > 16) {                          // rare overflow
        int4 e2a, e2b;
        float4 r0, r1, r2, r3, r4, r5, r6, r7;
        READC(e2a, e2b, list1b, 2);
        ISS8Q(r, e2a, e2b, w1zb);
        CONS8Q(a1v, r);
        if (n1 > 24) {
          READC(e2a, e2b, list1b, 3);
          ISS8Q(r, e2a, e2b, w1zb);
          CONS8Q(a1v, r);
        }
        if (n1 > 32) {
          #pragma unroll 1
          for (int g = 4; g * 8 < n1; ++g) {
            READC(e2a, e2b, list1b, g);
            ISS8Q(r, e2a, e2b, w1zb);
            CONS8Q(a1v, r);
          }
        }
      }
      // LIF layer 1, flattened
      const float a1arr[4] = {a1v.x + s0v.x, a1v.y + s0v.y,
                              a1v.z + s0v.z, a1v.w + s0v.w};
      float s1w[4];
      bool sq[4];
      unsigned long long nn0, nn1, nn2, nn3;
      {
        float u, v;
        u = b1z[0] + a1arr[0]; v = v1k[0] + (u - v1k[0]) * 0.5f;
        sq[0] = (v >= 1.0f); nn0 = __ballot(sq[0] ? 1 : 0);
        s1w[0] = sq[0] ? 1.0f : 0.0f; v1k[0] = sq[0] ? 0.0f : v;
        u = b1z[1] + a1arr[1]; v = v1k[1] + (u - v1k[1]) * 0.5f;
        sq[1] = (v >= 1.0f); nn1 = __ballot(sq[1] ? 1 : 0);
        s1w[1] = sq[1] ? 1.0f : 0.0f; v1k[1] = sq[1] ? 0.0f : v;
        u = b1z[2] + a1arr[2]; v = v1k[2] + (u - v1k[2]) * 0.5f;
        sq[2] = (v >= 1.0f); nn2 = __ballot(sq[2] ? 1 : 0);
        s1w[2] = sq[2] ? 1.0f : 0.0f; v1k[2] = sq[2] ? 0.0f : v;
        u = b1z[3] + a1arr[3]; v = v1k[3] + (u - v1k[3]) * 0.5f;
        sq[3] = (v >= 1.0f); nn3 = __ballot(sq[3] ? 1 : 0);
        s1w[3] = sq[3] ? 1.0f : 0.0f; v1k[3] = sq[3] ? 0.0f : v;
      }
      cntk[0] += s1w[0]; cntk[1] += s1w[1]; cntk[2] += s1w[2]; cntk[3] += s1w[3];
      // branchless compaction (junk slots; pad value 0 -> zero row)
      const int r0c  = (int)__popcll(nn0);
      const int r01  = r0c + (int)__popcll(nn1);
      const int r012 = r01 + (int)__popcll(nn2);
      const int p1n  = r012 + (int)__popcll(nn3);
      const int jk = 256 + ln;
      {
        int s;
        s = sq[0] ? lanecnt_lt(nn0)          : jk; *(int*)(list1b + 4 * s) = vo + ROWB;
        s = sq[1] ? (r0c  + lanecnt_lt(nn1)) : jk; *(int*)(list1b + 4 * s) = vo + 2 * ROWB;
        s = sq[2] ? (r01  + lanecnt_lt(nn2)) : jk; *(int*)(list1b + 4 * s) = vo + 3 * ROWB;
        s = sq[3] ? (r012 + lanecnt_lt(nn3)) : jk; *(int*)(list1b + 4 * s) = vo + 4 * ROWB;
      }
      *(int*)(list1b + 4 * (p1n + ln)) = 0;        // unconditional pads
      // read chunks + issue next gather (full-iteration flight)
      if (i + 1 < TT) {
        int4 d0a, d0b, d1a, d1b;
        asm volatile("" ::: "memory");
        READC(d0a, d0b, list1b, 0);
        READC(d1a, d1b, list1b, 1);
        ISS8Q(gA, d0a, d0b, w1zb);
        if (p1n > 8) ISS8Q(gB, d1a, d1b, w1zb);
      }
      n1 = p1n;
      // signal consumption (after the slot read, program order + fence)
      asm volatile("" ::: "memory");
      if (ln == 0) *vcons = i + 1;
    }

    // ---- epilogue (wave1 only): exact mean + head GEMV ----
    if (ln < 48) {
      const float r = 1.0f / 2048.0f;
      ((float4*)feat)[ln] =
          make_float4(cntk[0] * r, cntk[1] * r, cntk[2] * r, cntk[3] * r);
    }
    asm volatile("" ::: "memory");
    if (ln < NCLS) {
      float a = b_head[ln];
      const float* wh = W_head + ln * HN;
      #pragma unroll 8
      for (int q = 0; q < HN; ++q) a += feat[q] * wh[q];
      out[b * NCLS + ln] = a;
    }
  }
}

extern "C" void kernel_launch(void* const* d_in, const int* in_sizes, int n_in,
                              void* d_out, int out_size, void* d_ws, size_t ws_size,
                              hipStream_t stream) {
  const float* x       = (const float*)d_in[0];
  const float* W_in    = (const float*)d_in[1];
  const float* b_in    = (const float*)d_in[2];
  const float* W_cells = (const float*)d_in[3];
  const float* b_cells = (const float*)d_in[4];
  const float* W_head  = (const float*)d_in[5];
  const float* b_head  = (const float*)d_in[6];
  float* out = (float*)d_out;
  float* ws  = (float*)d_ws;   // 296704 bytes used

  snn_pack_k<<<(2 * HN * HN + 512 + 255) / 256, 256, 0, stream>>>(W_cells, ws);
  snn_main_k<<<128, 128, LDS_TOTAL, stream>>>(
      x, W_in, b_in, b_cells, W_head, b_head, ws, out);
}

// Round 16
// 861.631 us; speedup vs baseline: 1.9068x; 1.1991x over previous
//
#include <hip/hip_runtime.h>

#define HN 192
#define TT 2048
#define NCLS 12
#define ROWB 768
// LDS layout (bytes)
#define L0_PAD    147456           // 2048B zero region (pad reads land here)
#define LDS_LIST0 149504           // 1024B data slots + 256B junk
#define LDS_LIST1 150784           // same for layer 1
#define LDS_S0    152064           // 2 x 1024B s0 double buffer (parity)
#define LDS_FEAT  154112           // 768B
#define LDS_TOTAL 154880

// ws layout (floats): [w0 rows 0..191][zero row][w1 rows 0..191][1024B pad]
__global__ void snn_pack_k(const float* __restrict__ Wc, float* __restrict__ ws) {
  int idx = blockIdx.x * 256 + threadIdx.x;
  if (idx < HN * HN) {                       // layer 0: Wc[0][i][j] -> ws[j*192+i]
    int i = idx / HN, j = idx % HN;
    ws[j * HN + i] = Wc[idx];
  } else if (idx < 2 * HN * HN) {            // layer 1 -> rows 193..384
    int r = idx - HN * HN;
    int i = r / HN, j = r % HN;
    ws[(193 + j) * HN + i] = Wc[idx];
  } else {
    int r = idx - 2 * HN * HN;
    if (r < HN) ws[192 * HN + r] = 0.0f;     // zero row
    if (r < 256) ws[385 * HN + r] = 0.0f;    // tail pad
  }
}

__device__ __forceinline__ float4 add4(float4 a, float4 b) {
  return make_float4(a.x + b.x, a.y + b.y, a.z + b.z, a.w + b.w);
}
__device__ __forceinline__ int lanecnt_lt(unsigned long long m) {
  return __builtin_amdgcn_mbcnt_hi((unsigned)(m >> 32),
           __builtin_amdgcn_mbcnt_lo((unsigned)m, 0u));
}

#define READC(da, db, base, c) do { \
  da = *(const int4*)((base) + (c) * 32); \
  db = *(const int4*)((base) + (c) * 32 + 16); } while (0)

#define ISS8Q(p, ca, cb, basep) do { \
  p##0 = *(const float4*)((basep) + (unsigned)(ca).x + ln16); \
  p##1 = *(const float4*)((basep) + (unsigned)(ca).y + ln16); \
  p##2 = *(const float4*)((basep) + (unsigned)(ca).z + ln16); \
  p##3 = *(const float4*)((basep) + (unsigned)(ca).w + ln16); \
  p##4 = *(const float4*)((basep) + (unsigned)(cb).x + ln16); \
  p##5 = *(const float4*)((basep) + (unsigned)(cb).y + ln16); \
  p##6 = *(const float4*)((basep) + (unsigned)(cb).z + ln16); \
  p##7 = *(const float4*)((basep) + (unsigned)(cb).w + ln16); } while (0)

#define CONS8Q(acc, p) acc = add4(acc, \
  add4(add4(add4(p##0, p##1), add4(p##2, p##3)), \
       add4(add4(p##4, p##5), add4(p##6, p##7))))

// 2 waves per batch, one-step-lagged pipeline (r10 structure): wave0 layer 0
// (LDS W0 gather), wave1 layer 1 (global W1 gather, full-iteration flight).
// Branchless compaction (cndmask'd addresses into a junk region),
// unconditional pads, unconditional group-0 issue/consume, unconditional
// s0 publish (1024B slots).  One raw s_barrier per step; memory clobbers
// fence the compiler, no sched_barrier (lets the scheduler pipeline freely).
__global__ __launch_bounds__(128, 1) void snn_main_k(
    const float* __restrict__ x, const float* __restrict__ W_in,
    const float* __restrict__ b_in, const float* __restrict__ b_cells,
    const float* __restrict__ W_head, const float* __restrict__ b_head,
    const float* __restrict__ ws, float* __restrict__ out)
{
  extern __shared__ char lds[];
  const int tid = threadIdx.x;
  const int ln  = tid & 63;
  const bool isW0 = (tid < 64);
  const int b   = blockIdx.x;
  const unsigned ln16 = (unsigned)ln << 4;
  const char* ldsb = lds;
  char* list0b = lds + LDS_LIST0;
  char* list1b = lds + LDS_LIST1;
  float* feat  = (float*)(lds + LDS_FEAT);
  const char* w1zb = (const char*)ws + 192 * ROWB;   // zero row = L1 offset base

  // stage W0 (9216 float4) + 2048B zero guard (both waves)
  {
    const float4* src = (const float4*)ws;
    float4* dst = (float4*)lds;
    for (int i = tid; i < (192 * ROWB) / 16; i += 128) dst[i] = src[i];
    ((float4*)(lds + L0_PAD))[tid] = make_float4(0.f, 0.f, 0.f, 0.f);
  }
  __syncthreads();

  // opaque zero: forces x loads to VMEM so lgkm counter stays purely DS
  int vz;
  asm volatile("v_mov_b32 %0, 0" : "=v"(vz));

  // per-lane constants (4 neurons/lane in both layers; lanes 48-63 parked)
  float wi0[4], wi1[4], wi2[4], zb[4], b1z[4];
  #pragma unroll
  for (int k = 0; k < 4; ++k) {
    int i = 4 * ln + k;
    bool a = (i < HN);
    int ii = a ? i : 0;
    wi0[k] = a ? W_in[ii * 3 + 0] : 0.f;
    wi1[k] = a ? W_in[ii * 3 + 1] : 0.f;
    wi2[k] = a ? W_in[ii * 3 + 2] : 0.f;
    zb[k]  = a ? (b_in[ii] + b_cells[ii]) : -1e30f;
    b1z[k] = a ? b_cells[HN + ii] : -1e30f;
  }
  const float* __restrict__ xb = x + (size_t)b * TT * 3;
  const int vo = ln * 3072;

  // wave0 state: chunks preset to pad offsets (iter0 gathers zeros)
  float v0k[4] = {0, 0, 0, 0};
  int n0 = 0;
  int4 c0a = {L0_PAD,L0_PAD,L0_PAD,L0_PAD}, c0b = c0a, c1a = c0a, c1b = c0a;
  float x0 = xb[vz + 0], x1 = xb[vz + 1], x2 = xb[vz + 2];
  // wave1 state
  float v1k[4] = {0, 0, 0, 0}, cntk[4] = {0, 0, 0, 0};
  int n1 = 0;
  float4 gA0, gA1, gA2, gA3, gA4, gA5, gA6, gA7;
  float4 gB0, gB1, gB2, gB3, gB4, gB5, gB6, gB7;
  if (!isW0) {
    // pre-loop: issue an initial pad gather (zero row) so iter1's consume is safe
    int4 dz = {0, 0, 0, 0};
    ISS8Q(gA, dz, dz, w1zb);
    gB0=gB1=gB2=gB3=gB4=gB5=gB6=gB7=make_float4(0.f,0.f,0.f,0.f);
  }

  #pragma unroll 1
  for (int i = 0; i <= TT; ++i) {
    if (isW0) {
      if (i < TT) {
        // ======== wave 0: layer-0 step i ========
        const int wp = i & 1;
        float4 a0v = make_float4(0.f, 0.f, 0.f, 0.f);
        float4 hA0, hA1, hA2, hA3, hA4, hA5, hA6, hA7;
        float4 hB0, hB1, hB2, hB3, hB4, hB5, hB6, hB7;
        ISS8Q(hA, c0a, c0b, ldsb);             // unconditional group 0
        if (n0 > 8) ISS8Q(hB, c1a, c1b, ldsb);
        // input projection (carried x) + next-x prefetch (VMEM, in flight)
        float zarr[4];
        #pragma unroll
        for (int k = 0; k < 4; ++k)
          zarr[k] = x0 * wi0[k] + x1 * wi1[k] + x2 * wi2[k] + zb[k];
        const int tn = (i + 1 < TT) ? i + 1 : 0;
        const float nx0 = xb[tn * 3 + vz + 0];
        const float nx1 = xb[tn * 3 + vz + 1];
        const float nx2 = xb[tn * 3 + vz + 2];
        CONS8Q(a0v, hA);
        if (n0 > 8) CONS8Q(a0v, hB);
        if (n0 > 16) {                          // rare overflow: chunks 2..3 + loop
          int4 e2a, e2b;
          float4 r0, r1, r2, r3, r4, r5, r6, r7;
          READC(e2a, e2b, list0b, 2);
          ISS8Q(r, e2a, e2b, ldsb);
          CONS8Q(a0v, r);
          if (n0 > 24) {
            READC(e2a, e2b, list0b, 3);
            ISS8Q(r, e2a, e2b, ldsb);
            CONS8Q(a0v, r);
          }
          if (n0 > 32) {
            #pragma unroll 1
            for (int g = 4; g * 8 < n0; ++g) {
              READC(e2a, e2b, list0b, g);
              ISS8Q(r, e2a, e2b, ldsb);
              CONS8Q(a0v, r);
            }
          }
        }
        // LIF layer 0 (exact reference op order), flattened
        const float a0arr[4] = {a0v.x, a0v.y, a0v.z, a0v.w};
        float s0f[4];
        bool sp[4];
        unsigned long long mm0, mm1, mm2, mm3;
        {
          float u, v;
          u = zarr[0] + a0arr[0]; v = v0k[0] + (u - v0k[0]) * 0.5f;
          sp[0] = (v >= 1.0f); mm0 = __ballot(sp[0] ? 1 : 0);
          s0f[0] = sp[0] ? 1.0f : 0.0f; v0k[0] = sp[0] ? 0.0f : v;
          u = zarr[1] + a0arr[1]; v = v0k[1] + (u - v0k[1]) * 0.5f;
          sp[1] = (v >= 1.0f); mm1 = __ballot(sp[1] ? 1 : 0);
          s0f[1] = sp[1] ? 1.0f : 0.0f; v0k[1] = sp[1] ? 0.0f : v;
          u = zarr[2] + a0arr[2]; v = v0k[2] + (u - v0k[2]) * 0.5f;
          sp[2] = (v >= 1.0f); mm2 = __ballot(sp[2] ? 1 : 0);
          s0f[2] = sp[2] ? 1.0f : 0.0f; v0k[2] = sp[2] ? 0.0f : v;
          u = zarr[3] + a0arr[3]; v = v0k[3] + (u - v0k[3]) * 0.5f;
          sp[3] = (v >= 1.0f); mm3 = __ballot(sp[3] ? 1 : 0);
          s0f[3] = sp[3] ? 1.0f : 0.0f; v0k[3] = sp[3] ? 0.0f : v;
        }
        // publish s0(i) — unconditional (1024B slot; parked lanes write 0)
        *(float4*)(lds + LDS_S0 + (wp << 10) + ln16) =
            make_float4(s0f[0], s0f[1], s0f[2], s0f[3]);
        // branchless compaction: cndmask'd slot (junk slots at 256+ln)
        const int q0   = (int)__popcll(mm0);
        const int q01  = q0  + (int)__popcll(mm1);
        const int q012 = q01 + (int)__popcll(mm2);
        const int p0n  = q012 + (int)__popcll(mm3);
        const int jk = 256 + ln;
        {
          int s;
          s = sp[0] ? lanecnt_lt(mm0)          : jk; *(int*)(list0b + 4 * s) = vo;
          s = sp[1] ? (q0   + lanecnt_lt(mm1)) : jk; *(int*)(list0b + 4 * s) = vo + ROWB;
          s = sp[2] ? (q01  + lanecnt_lt(mm2)) : jk; *(int*)(list0b + 4 * s) = vo + 2 * ROWB;
          s = sp[3] ? (q012 + lanecnt_lt(mm3)) : jk; *(int*)(list0b + 4 * s) = vo + 3 * ROWB;
        }
        *(int*)(list0b + 4 * (p0n + ln)) = L0_PAD;   // unconditional pads
        n0 = p0n;
        asm volatile("" ::: "memory");
        READC(c0a, c0b, list0b, 0);
        READC(c1a, c1b, list0b, 1);
        // oldest DS ops (s0 publish, compaction) retired; chunk reads stay out
        asm volatile("s_waitcnt lgkmcnt(8)" ::: "memory");
        x0 = nx0; x1 = nx1; x2 = nx2;
      }
    } else {
      if (i > 0) {
        // ======== wave 1: layer-1 step i-1 ========
        const int rp = (i - 1) & 1;
        const float4 s0v = *(const float4*)(lds + LDS_S0 + (rp << 10) + ln16);
        // consume W1 gather (issued at end of previous block -> real flight)
        float4 a1v = make_float4(0.f, 0.f, 0.f, 0.f);
        CONS8Q(a1v, gA);                        // unconditional group 0
        if (n1 > 8) CONS8Q(a1v, gB);
        if (n1 > 16) {                          // rare overflow
          int4 e2a, e2b;
          float4 r0, r1, r2, r3, r4, r5, r6, r7;
          READC(e2a, e2b, list1b, 2);
          ISS8Q(r, e2a, e2b, w1zb);
          CONS8Q(a1v, r);
          if (n1 > 24) {
            READC(e2a, e2b, list1b, 3);
            ISS8Q(r, e2a, e2b, w1zb);
            CONS8Q(a1v, r);
          }
          if (n1 > 32) {
            #pragma unroll 1
            for (int g = 4; g * 8 < n1; ++g) {
              READC(e2a, e2b, list1b, g);
              ISS8Q(r, e2a, e2b, w1zb);
              CONS8Q(a1v, r);
            }
          }
        }
        // LIF layer 1, flattened
        const float a1arr[4] = {a1v.x + s0v.x, a1v.y + s0v.y,
                                a1v.z + s0v.z, a1v.w + s0v.w};
        float s1w[4];
        bool sq[4];
        unsigned long long nn0, nn1, nn2, nn3;
        {
          float u, v;
          u = b1z[0] + a1arr[0]; v = v1k[0] + (u - v1k[0]) * 0.5f;
          sq[0] = (v >= 1.0f); nn0 = __ballot(sq[0] ? 1 : 0);
          s1w[0] = sq[0] ? 1.0f : 0.0f; v1k[0] = sq[0] ? 0.0f : v;
          u = b1z[1] + a1arr[1]; v = v1k[1] + (u - v1k[1]) * 0.5f;
          sq[1] = (v >= 1.0f); nn1 = __ballot(sq[1] ? 1 : 0);
          s1w[1] = sq[1] ? 1.0f : 0.0f; v1k[1] = sq[1] ? 0.0f : v;
          u = b1z[2] + a1arr[2]; v = v1k[2] + (u - v1k[2]) * 0.5f;
          sq[2] = (v >= 1.0f); nn2 = __ballot(sq[2] ? 1 : 0);
          s1w[2] = sq[2] ? 1.0f : 0.0f; v1k[2] = sq[2] ? 0.0f : v;
          u = b1z[3] + a1arr[3]; v = v1k[3] + (u - v1k[3]) * 0.5f;
          sq[3] = (v >= 1.0f); nn3 = __ballot(sq[3] ? 1 : 0);
          s1w[3] = sq[3] ? 1.0f : 0.0f; v1k[3] = sq[3] ? 0.0f : v;
        }
        cntk[0] += s1w[0]; cntk[1] += s1w[1]; cntk[2] += s1w[2]; cntk[3] += s1w[3];
        // branchless compaction (junk slots at 256+ln; pad value 0 -> zero row)
        const int r0c  = (int)__popcll(nn0);
        const int r01  = r0c + (int)__popcll(nn1);
        const int r012 = r01 + (int)__popcll(nn2);
        const int p1n  = r012 + (int)__popcll(nn3);
        const int jk = 256 + ln;
        {
          int s;
          s = sq[0] ? lanecnt_lt(nn0)          : jk; *(int*)(list1b + 4 * s) = vo + ROWB;
          s = sq[1] ? (r0c  + lanecnt_lt(nn1)) : jk; *(int*)(list1b + 4 * s) = vo + 2 * ROWB;
          s = sq[2] ? (r01  + lanecnt_lt(nn2)) : jk; *(int*)(list1b + 4 * s) = vo + 3 * ROWB;
          s = sq[3] ? (r012 + lanecnt_lt(nn3)) : jk; *(int*)(list1b + 4 * s) = vo + 4 * ROWB;
        }
        *(int*)(list1b + 4 * (p1n + ln)) = 0;        // unconditional pads
        // read chunks + issue next gather (flight = tail + barrier + preamble)
        if (i < TT) {
          int4 d0a, d0b, d1a, d1b;
          asm volatile("" ::: "memory");
          READC(d0a, d0b, list1b, 0);
          READC(d1a, d1b, list1b, 1);
          ISS8Q(gA, d0a, d0b, w1zb);               // unconditional group 0
          if (p1n > 8) ISS8Q(gB, d1a, d1b, w1zb);
        }
        n1 = p1n;
      }
    }
    asm volatile("" ::: "memory");
    __builtin_amdgcn_s_barrier();
    asm volatile("" ::: "memory");
  }

  __syncthreads();
  // epilogue: exact mean (count * 2^-11) + head GEMV
  if (!isW0 && ln < 48) {
    const float r = 1.0f / 2048.0f;
    ((float4*)feat)[ln] = make_float4(cntk[0] * r, cntk[1] * r, cntk[2] * r, cntk[3] * r);
  }
  __syncthreads();
  if (tid < NCLS) {
    float a = b_head[tid];
    const float* wh = W_head + tid * HN;
    #pragma unroll 8
    for (int q = 0; q < HN; ++q) a += feat[q] * wh[q];
    out[b * NCLS + tid] = a;
  }
}

extern "C" void kernel_launch(void* const* d_in, const int* in_sizes, int n_in,
                              void* d_out, int out_size, void* d_ws, size_t ws_size,
                              hipStream_t stream) {
  const float* x       = (const float*)d_in[0];
  const float* W_in    = (const float*)d_in[1];
  const float* b_in    = (const float*)d_in[2];
  const float* W_cells = (const float*)d_in[3];
  const float* b_cells = (const float*)d_in[4];
  const float* W_head  = (const float*)d_in[5];
  const float* b_head  = (const float*)d_in[6];
  float* out = (float*)d_out;
  float* ws  = (float*)d_ws;   // 296704 bytes used

  snn_pack_k<<<(2 * HN * HN + 512 + 255) / 256, 256, 0, stream>>>(W_cells, ws);
  snn_main_k<<<128, 128, LDS_TOTAL, stream>>>(
      x, W_in, b_in, b_cells, W_head, b_head, ws, out);
}